// Round 8
// baseline (503.533 us; speedup 1.0000x reference)
//
#include <hip/hip_runtime.h>
#include <math.h>
#include <float.h>

#define B 8
#define N 4096
#define C 512
#define K 130
#define KP 144
#define BNK (B*N*K)
#define SB(s,b) ((s)*B + (b))

typedef __bf16 bf16x8 __attribute__((ext_vector_type(8)));
typedef __bf16 bf16x4 __attribute__((ext_vector_type(4)));
typedef float  f32x4  __attribute__((ext_vector_type(4)));

// ws layout (bytes); total ~86 MB (proven-safe: R1 ran at 160 MB)
#define SZ_KQ   18874368ull                 // bf16 [2][B][KP][N]
#define SLAB    1179648ull                  // floats per zpart slab: 16*KP*C
#define OFS_KQH 0ull
#define OFS_KQL (OFS_KQH + SZ_KQ)
#define OFS_ZP  (OFS_KQL + SZ_KQ)           // float [8][16][KP][C] partials
#define OFS_ZT  (OFS_ZP + 8ull*SLAB*4ull)   // reused: nzp partial sumsq [16][KP][32]
#define OFS_ZH  (OFS_ZT + SLAB*4ull)        // bf16
#define OFS_ZL  (OFS_ZH + SLAB*2ull)
#define OFS_NKI (OFS_ZL + SLAB*2ull)
#define OFS_NZI (OFS_NKI + 9216ull)
#define OFS_NKP (OFS_NZI + 9216ull)         // float [16][KP][64] kq sumsq partials

__device__ __forceinline__ void split2(float v, __bf16& h, __bf16& l) {
    h = (__bf16)v;
    l = (__bf16)(v - (float)h);
}
// split into ext-vector elements (can't bind refs to vector elements)
#define SPLIT_VEC(v, vh, vl, i) { __bf16 _h = (__bf16)(v); (vh)[i] = _h; (vl)[i] = (__bf16)((v) - (float)_h); }

// async global->LDS, 16B per lane; LDS dest = wave-uniform base + lane*16
__device__ __forceinline__ void gl_lds16(const void* g, void* l) {
    __builtin_amdgcn_global_load_lds(
        (const __attribute__((address_space(1))) void*)g,
        (__attribute__((address_space(3))) void*)l, 16, 0, 0);
}

// window max for one half: v = own chunk [4l,4l+4), u = next 4 elems [4l+4,4l+8)
// window = [4l+r, 4l+4+t): max(suffix of v from r, prefix of u of t elems)
__device__ __forceinline__ float wmax(float4 v, float4 u, int r, int tt, float& sm0out) {
    float sm3 = v.w;
    float sm2 = fmaxf(v.z, sm3);
    float sm1 = fmaxf(v.y, sm2);
    float sm0 = fmaxf(v.x, sm1);
    sm0out = sm0;
    float smr = (r == 3) ? sm3 : (r == 2) ? sm2 : (r == 1) ? sm1 : sm0;
    float pu1 = u.x;
    float pu2 = fmaxf(pu1, u.y);
    float pu3 = fmaxf(pu2, u.z);
    float pu4 = fmaxf(pu3, u.w);
    float put = (tt == 4) ? pu4 : (tt == 3) ? pu3 : (tt == 2) ? pu2 :
                (tt == 1) ? pu1 : -FLT_MAX;
    return fmaxf(smr, put);
}

// ---------- adaptive max pool from fp32 x -> kq hi/lo [s][b][kk][n] ----------
// v8: v7 ring pipeline kept (pool parked at ~60us: two structurally different
// pipelines (v6 barrier-dbuf, v7 counted-vmcnt ring) measure identical ->
// throughput-resource-bound, not latency). NEW: emit per-block kq sumsq
// partials (nkp) so the full-kq-reread knorm kernel is eliminated.
__global__ __launch_bounds__(256) void pool_kernel(const float* __restrict__ x1,
        const float* __restrict__ x2, __bf16* __restrict__ kqh, __bf16* __restrict__ kql,
        float* __restrict__ nkp)
{
    int s = blockIdx.y;
    const float* x = s ? x2 : x1;
    int bx = blockIdx.x;                 // nch(64) * b(8)
    int nch = bx & 63, b = bx >> 6;
    int n0 = nch * 64;
    int t = threadIdx.x, w = t >> 6, l = t & 63;
    int sb = SB(s,b);

    // [0,8192): ring slots: wave w slot q at (w*4+q)*512 floats (2KB/slot)
    // [8192,...): pooled[KP][69]
    __shared__ __align__(16) float spool[8192 + KP * 69 + 8];
    float* pooled = spool + 8192;

    // per-lane window geometry (constant): lane l owns window kk=l+1 per half
    int kkA = l + 1;
    int sA  = (kkA * 256) / 65;               // start (floor)
    int eA  = ((kkA + 1) * 256 + 64) / 65;    // end (ceil)
    int rwin = sA - 4 * l;                    // 0..3
    int tt   = eA - 4 * l - 4;                // 0..4

    size_t xbase = (size_t)(b * N + n0) * C;

#define ISSUE_ROW(rl, slot) { \
        const float* src_ = x + xbase + (size_t)(w * 16 + (rl)) * C + 4 * l; \
        char* dst_ = (char*)spool + (w * 4 + (slot)) * 2048; \
        gl_lds16(src_, dst_); \
        gl_lds16(src_ + 256, dst_ + 1024); \
    }

#define COMP_ROW(rl) { \
        const float* xr_ = spool + (w * 4 + ((rl) & 3)) * 512; \
        float4 vA = *(const float4*)(xr_ + 4 * l); \
        float4 uA = *(const float4*)(xr_ + 4 * l + 4); \
        float4 vB = *(const float4*)(xr_ + 256 + 4 * l); \
        float4 uB = *(const float4*)(xr_ + 256 + 4 * l + 4); \
        float sm0A, sm0B; \
        float mA = wmax(vA, uA, rwin, tt, sm0A); \
        float mB = wmax(vB, uB, rwin, tt, sm0B); \
        int n_ = w * 16 + (rl); \
        pooled[kkA * 69 + n_] = mA; \
        pooled[(kkA + 65) * 69 + n_] = mB; \
        if (l == 0) { pooled[n_] = sm0A; pooled[65 * 69 + n_] = sm0B; } \
    }

#define POOL_STEP(rl, VMC) \
    asm volatile("s_waitcnt vmcnt(" #VMC ")" ::: "memory"); \
    __builtin_amdgcn_sched_barrier(0); \
    COMP_ROW(rl) \
    __builtin_amdgcn_sched_barrier(0); \
    if ((rl) + 4 < 16) ISSUE_ROW((rl) + 4, (rl) & 3)

    // prologue: fill the ring
    ISSUE_ROW(0, 0) ISSUE_ROW(1, 1) ISSUE_ROW(2, 2) ISSUE_ROW(3, 3)

    POOL_STEP(0, 6);  POOL_STEP(1, 6);  POOL_STEP(2, 6);  POOL_STEP(3, 6);
    POOL_STEP(4, 6);  POOL_STEP(5, 6);  POOL_STEP(6, 6);  POOL_STEP(7, 6);
    POOL_STEP(8, 6);  POOL_STEP(9, 6);  POOL_STEP(10, 6); POOL_STEP(11, 6);
    POOL_STEP(12, 6); POOL_STEP(13, 4); POOL_STEP(14, 2); POOL_STEP(15, 0);

#undef POOL_STEP
#undef COMP_ROW
#undef ISSUE_ROW

    __syncthreads();
    // 288 tasks (kk x {hi,lo}); 8 lanes cover one kk-row's 64 n = 128B contiguous.
    // Hi tasks additionally emit per-(kk, 64n-chunk) sumsq of (hi+lo) -> nkp.
    int g = t >> 3, j = t & 7;
    #pragma unroll
    for (int p = 0; p < 9; ++p) {
        int task = p * 32 + g;           // < 288; uniform across each 8-lane group
        int a = task >= 144;
        int kk = task - (a ? 144 : 0);
        bf16x8 v8;
        float ss = 0.f;
        #pragma unroll
        for (int e = 0; e < 8; ++e) {
            float val = (kk < K) ? pooled[kk * 69 + j * 8 + e] : 0.f;
            __bf16 h = (__bf16)val;
            __bf16 lo = (__bf16)(val - (float)h);
            v8[e] = a ? lo : h;
            float rec = (float)h + (float)lo;
            ss = fmaf(rec, rec, ss);
        }
        __bf16* dst = a ? kql : kqh;
        *(bf16x8*)(dst + ((size_t)(sb * KP + kk)) * N + n0 + j * 8) = v8;
        if (!a) {
            ss += __shfl_xor(ss, 1, 8);
            ss += __shfl_xor(ss, 2, 8);
            ss += __shfl_xor(ss, 4, 8);
            if (j == 0) nkp[((size_t)(sb * KP + kk)) * 64 + nch] = ss;
        }
    }
}

// ---------- knorm reduce: combine cnt sumsq partials per kq row ----------
__global__ __launch_bounds__(256) void knorm_reduce(const float* __restrict__ nkp,
        float* __restrict__ nkinv, int cnt)
{
    int s = blockIdx.y;
    int idx = blockIdx.x * 256 + threadIdx.x;  // < B*KP
    if (idx >= B * KP) return;
    const float* p = nkp + ((size_t)(s * B * KP) + idx) * 64;
    float sum = 0.f;
    for (int i = 0; i < cnt; ++i) sum += p[i];
    nkinv[s * B * KP + idx] = 1.f / (1e-6f + sqrtf(sum));
}

// ---------- GEMM1 (split): zpart[p][kk][c] = sum_n kq[kk][n]*x[n][c] * nkinv[kk] ----------
// v3: kq hi/lo LDS-staged (global_load_lds w=16, XOR-swizzled slots, double-buffered);
//     x staging register-prefetched (T14 issue-early/write-late).
// v4: XCD-aware block swizzle.
// LDS: x-tile 20.0KB + kq 2x18.0KB = 57.3KB -> 2 blocks/CU, 8 waves/CU.
__device__ __forceinline__ void stage_kq(const __bf16* kqh, const __bf16* kql,
        size_t kqbase, int nb, int gsl, char* buf, int w, int l)
{
    #pragma unroll
    for (int i = 0; i < 5; ++i) {
        int j = i * 4 + w;               // 18 wave-issues: w gets {w, 4+w, 8+w, 12+w, 16+w<18}
        if (j < 18) {
            int rbase = j * 16;          // LDS rows rbase..rbase+15 (hi: 0..143, lo: 144..287)
            int kk = rbase + (l >> 2) - (j >= 9 ? 144 : 0);
            const __bf16* bp = (j >= 9) ? kql : kqh;
            gl_lds16(bp + kqbase + (size_t)kk * N + nb + gsl, buf + rbase * 64);
        }
    }
}

__global__ __launch_bounds__(256, 2) void gemm1_kernel(const float* __restrict__ x1,
        const float* __restrict__ x2, const __bf16* __restrict__ kqh,
        const __bf16* __restrict__ kql, const float* __restrict__ nkinv,
        float* __restrict__ zpart)
{
    int s = blockIdx.y;
    const float* x = s ? x2 : x1;
    int orig = blockIdx.x;               // 256 blocks: XCD swizzle (256%8==0, bijective)
    int wid = (orig & 7) * 32 + (orig >> 3);
    int cs = wid & 3, b = (wid >> 2) & 7, nsp = wid >> 5;
    int sb = SB(s,b);
    int c0 = cs * 128, n0 = nsp * 512;
    int t = threadIdx.x, w = t >> 6, l = t & 63, quad = l >> 4, lm = l & 15;

    __shared__ __bf16 ldsh[128 * 40];
    __shared__ __bf16 ldsl[128 * 40];
    __shared__ __align__(16) char kbuf[2][18432];  // [288 rows][64B], slot^((row>>1)&3)

    f32x4 acc[9][2];
    #pragma unroll
    for (int kkt = 0; kkt < 9; ++kkt)
        #pragma unroll
        for (int ct = 0; ct < 2; ++ct) { acc[kkt][ct][0]=0.f; acc[kkt][ct][1]=0.f; acc[kkt][ct][2]=0.f; acc[kkt][ct][3]=0.f; }

    int cload = t & 127;                 // staging c
    int ngrp = t >> 7;                   // staging n group (0/1)
    size_t kqbase = (size_t)(sb * KP) * N;
    int gsl = ((l & 3) ^ ((l >> 3) & 3)) * 8;      // inverse-swizzled src n-offset (elements)

    // prologue: x regs + kq chunk 0
    float xr[16];
    {
        const float* xs = x + (size_t)(b * N + n0 + ngrp * 16) * C + c0 + cload;
        #pragma unroll
        for (int p = 0; p < 16; ++p) xr[p] = xs[(size_t)p * C];
        stage_kq(kqh, kql, kqbase, n0, gsl, kbuf[0], w, l);
    }

    for (int step = 0; step < 16; ++step) {
        int nb = n0 + step * 32;
        __syncthreads();                 // prev x-tile consumed; kq(step)+xr(step) drained
        #pragma unroll
        for (int p = 0; p < 4; ++p) {    // split regs -> lds [c][n] hi/lo
            int nl = ngrp * 16 + p * 4;
            bf16x4 vh, vl;
            SPLIT_VEC(xr[p*4+0], vh, vl, 0); SPLIT_VEC(xr[p*4+1], vh, vl, 1);
            SPLIT_VEC(xr[p*4+2], vh, vl, 2); SPLIT_VEC(xr[p*4+3], vh, vl, 3);
            *(bf16x4*)(&ldsh[cload * 40 + nl]) = vh;
            *(bf16x4*)(&ldsl[cload * 40 + nl]) = vl;
        }
        __syncthreads();                 // x-tile ready
        if (step < 15) {                 // issue next-step kq + x; they fly under compute
            int nb2 = nb + 32;
            stage_kq(kqh, kql, kqbase, nb2, gsl, kbuf[(step + 1) & 1], w, l);
            const float* xs = x + (size_t)(b * N + nb2 + ngrp * 16) * C + c0 + cload;
            #pragma unroll
            for (int p = 0; p < 16; ++p) xr[p] = xs[(size_t)p * C];
        }
        const char* kb = kbuf[step & 1];
        bf16x8 bh[2], bl[2];
        #pragma unroll
        for (int ct = 0; ct < 2; ++ct) {
            int cl = w * 32 + ct * 16 + lm;
            bh[ct] = *(const bf16x8*)(&ldsh[cl * 40 + quad * 8]);
            bl[ct] = *(const bf16x8*)(&ldsl[cl * 40 + quad * 8]);
        }
        int arow = lm * 64 + ((quad ^ ((lm >> 1) & 3)) * 16);  // swizzled A-frag byte addr
        #pragma unroll
        for (int kkt = 0; kkt < 9; ++kkt) {
            bf16x8 ah = *(const bf16x8*)(kb + kkt * 1024 + arow);
            bf16x8 al = *(const bf16x8*)(kb + 9216 + kkt * 1024 + arow);
            #pragma unroll
            for (int ct = 0; ct < 2; ++ct) {
                acc[kkt][ct] = __builtin_amdgcn_mfma_f32_16x16x32_bf16(ah, bh[ct], acc[kkt][ct], 0, 0, 0);
                acc[kkt][ct] = __builtin_amdgcn_mfma_f32_16x16x32_bf16(al, bh[ct], acc[kkt][ct], 0, 0, 0);
                acc[kkt][ct] = __builtin_amdgcn_mfma_f32_16x16x32_bf16(ah, bl[ct], acc[kkt][ct], 0, 0, 0);
            }
        }
    }
    float* zp = zpart + ((size_t)nsp * 16 + sb) * KP * C;
    #pragma unroll
    for (int kkt = 0; kkt < 9; ++kkt) {
        #pragma unroll
        for (int i = 0; i < 4; ++i) {
            int kk = kkt * 16 + quad * 4 + i;
            float inv = nkinv[sb * KP + kk];
            #pragma unroll
            for (int ct = 0; ct < 2; ++ct) {
                int c = c0 + w * 32 + ct * 16 + lm;
                zp[(size_t)kk * C + c] = acc[kkt][ct][i] * inv;
            }
        }
    }
}

// ---------- softmax v2 (fused): sum 8 partials in LDS, softmax over kk,
// write zh/zl ONLY, emit per-block sumsq partials for znorm.
__global__ __launch_bounds__(256) void softmax_kernel(const float* __restrict__ zpart,
        __bf16* __restrict__ zh, __bf16* __restrict__ zl, float* __restrict__ nzp)
{
    int s = blockIdx.y;
    int bx = blockIdx.x;                 // b(8) * cb(32)
    int b = bx >> 5, cb = bx & 31;
    int c0 = cb * 16;
    int sb = SB(s,b);
    int t = threadIdx.x;
    int cl = t & 15, g = t >> 4;         // 16 kk-groups
    __shared__ float sm[KP * 17];
    __shared__ float inv[16];
    size_t base = (size_t)sb * KP * C + c0 + cl;

    // phase 1: sum the 8 n-split partials
    #pragma unroll
    for (int j = 0; j < 9; ++j) {
        int kk = g + 16 * j;             // covers 0..143
        size_t off = base + (size_t)kk * C;
        float v = 0.f;
        #pragma unroll
        for (int p = 0; p < 8; ++p)
            v += zpart[(size_t)p * SLAB + off];
        sm[kk * 17 + cl] = v;
    }
    __syncthreads();
    // phase 2: softmax over kk per c (16 threads per c)
    {
        int c = t >> 4, r = t & 15;
        float m = -FLT_MAX;
        for (int kk = r; kk < K; kk += 16) m = fmaxf(m, sm[kk * 17 + c]);
        m = fmaxf(m, __shfl_xor(m, 1, 64));
        m = fmaxf(m, __shfl_xor(m, 2, 64));
        m = fmaxf(m, __shfl_xor(m, 4, 64));
        m = fmaxf(m, __shfl_xor(m, 8, 64));
        float sum = 0.f;
        for (int kk = r; kk < K; kk += 16) {
            float e = expf(sm[kk * 17 + c] - m);
            sm[kk * 17 + c] = e;
            sum += e;
        }
        sum += __shfl_xor(sum, 1, 64);
        sum += __shfl_xor(sum, 2, 64);
        sum += __shfl_xor(sum, 4, 64);
        sum += __shfl_xor(sum, 8, 64);
        if (r == 0) inv[c] = 1.f / sum;
    }
    __syncthreads();
    // phase 3: scale, store zh/zl, per-kk sumsq partial over this 16-c slice
    #pragma unroll
    for (int j = 0; j < 9; ++j) {
        int kk = g + 16 * j;
        float val = (kk < K) ? sm[kk * 17 + cl] * inv[cl] : 0.f;
        __bf16 h, lo; split2(val, h, lo);
        size_t off = base + (size_t)kk * C;
        zh[off] = h;
        zl[off] = lo;
        float ss = val * val;
        #pragma unroll
        for (int o = 8; o; o >>= 1) ss += __shfl_xor(ss, o, 16);
        if (cl == 0) nzp[((size_t)sb * KP + kk) * 32 + cb] = ss;
    }
}

// ---------- znorm (tiny): combine 32 sumsq partials per kk-row ----------
__global__ __launch_bounds__(256) void znorm_kernel(const float* __restrict__ nzp,
        float* __restrict__ nzinv)
{
    int s = blockIdx.y;
    int idx = blockIdx.x * 256 + threadIdx.x;  // < B*KP
    if (idx >= B * KP) return;
    const float* p = nzp + ((size_t)(s * B * KP) + idx) * 32;
    float sum = 0.f;
    #pragma unroll
    for (int i = 0; i < 32; ++i) sum += p[i];
    nzinv[s * B * KP + idx] = 1.f / (1e-6f + sqrtf(sum));
}

// ---------- GEMM2 (split): out[n][kk] = sum_c x[n][c]*z[kk][c] * nzinv[kk] ----------
// v3: z hi/lo LDS-staged (gl_lds w=16, XOR-swizzled, double-buffered), 128 n/block,
//     XCD swizzle. NEW: out written only when wout (final stage); per-ntile kq
//     sumsq partials (nkp) emitted -> knorm's full-kq reread eliminated.
// LDS 80640 B -> 2 blocks/CU (161.3KB <= 160KiB*... 2x80640=161280 <= 163840).
__global__ __launch_bounds__(256, 2) void gemm2_kernel(const float* __restrict__ x1,
        const float* __restrict__ x2, const __bf16* __restrict__ zh,
        const __bf16* __restrict__ zl, const float* __restrict__ nzinv,
        float* __restrict__ out, __bf16* __restrict__ kqh, __bf16* __restrict__ kql,
        float* __restrict__ nkp, int wout)
{
    int s = blockIdx.y;
    const float* x = s ? x2 : x1;
    // XCD swizzle: 256 blocks, 8 XCDs -> each XCD gets one b's 32 n-tiles
    int orig = blockIdx.x;
    int bx = (orig & 7) * 32 + (orig >> 3);
    int ntile = bx & 31, b = bx >> 5, sb = SB(s,b);
    int n0 = ntile * 128;
    int t = threadIdx.x, w = t >> 6, l = t & 63, quad = l >> 4, lm = l & 15;

    __shared__ __align__(16) char smem[80640];
    float* wsum = (float*)(smem + 78336);    // [4][144]

    f32x4 acc[9][2];
    #pragma unroll
    for (int kkt = 0; kkt < 9; ++kkt)
        #pragma unroll
        for (int i = 0; i < 2; ++i) { acc[kkt][i][0]=0.f; acc[kkt][i][1]=0.f; acc[kkt][i][2]=0.f; acc[kkt][i][3]=0.f; }

    size_t zrb = (size_t)sb * KP * C;
    int lr = l >> 3, m8 = l & 7;
    // linear LDS dest + inverse-swizzled global source; read applies same XOR (rule #21)
    int csw = ((m8 ^ lr) * 8);

    // prologue: stage chunk 0 into buf0
    #pragma unroll
    for (int i = 0; i < 9; ++i) {
        int r0 = (w * 9 + i) * 8, row = r0 + lr;
        const __bf16* src = (row < KP) ? (zh + zrb + (size_t)row * C + csw)
                                       : (zl + zrb + (size_t)(row - KP) * C + csw);
        gl_lds16(src, smem + r0 * 128);
    }

    for (int it = 0; it < 8; ++it) {
        __syncthreads();                 // buf[it&1] staged (vmcnt drained at barrier)
        if (it < 7) {                    // issue next chunk into other buffer
            int cb2 = (it + 1) * 64;
            char* buf = smem + ((it + 1) & 1) * 36864;
            #pragma unroll
            for (int i = 0; i < 9; ++i) {
                int r0 = (w * 9 + i) * 8, row = r0 + lr;
                const __bf16* src = (row < KP) ? (zh + zrb + (size_t)row * C + cb2 + csw)
                                               : (zl + zrb + (size_t)(row - KP) * C + cb2 + csw);
                gl_lds16(src, buf + r0 * 128);
            }
        }
        const char* zb = smem + (it & 1) * 36864;
        int cb = it * 64;
        #pragma unroll
        for (int sub = 0; sub < 2; ++sub) {
            bf16x8 ah[2], al[2];
            #pragma unroll
            for (int i = 0; i < 2; ++i) {
                const float* Ab = x + (size_t)(b * N + n0 + w * 32 + i * 16 + lm) * C + cb + sub * 32 + quad * 8;
                float4 u = *(const float4*)Ab;
                float4 v = *(const float4*)(Ab + 4);
                SPLIT_VEC(u.x, ah[i], al[i], 0); SPLIT_VEC(u.y, ah[i], al[i], 1);
                SPLIT_VEC(u.z, ah[i], al[i], 2); SPLIT_VEC(u.w, ah[i], al[i], 3);
                SPLIT_VEC(v.x, ah[i], al[i], 4); SPLIT_VEC(v.y, ah[i], al[i], 5);
                SPLIT_VEC(v.z, ah[i], al[i], 6); SPLIT_VEC(v.w, ah[i], al[i], 7);
            }
            // kk&7 == lm&7 (16 | kkt stride), so swizzle term is kkt-invariant
            int sw = ((sub * 4 + quad) ^ (lm & 7)) * 16;
            #pragma unroll
            for (int kkt = 0; kkt < 9; ++kkt) {
                int kk = kkt * 16 + lm;
                const char* ph = zb + kk * 128 + sw;
                bf16x8 bh = *(const bf16x8*)ph;
                bf16x8 bl = *(const bf16x8*)(ph + KP * 128);
                #pragma unroll
                for (int i = 0; i < 2; ++i) {
                    acc[kkt][i] = __builtin_amdgcn_mfma_f32_16x16x32_bf16(ah[i], bh, acc[kkt][i], 0, 0, 0);
                    acc[kkt][i] = __builtin_amdgcn_mfma_f32_16x16x32_bf16(al[i], bh, acc[kkt][i], 0, 0, 0);
                    acc[kkt][i] = __builtin_amdgcn_mfma_f32_16x16x32_bf16(ah[i], bl, acc[kkt][i], 0, 0, 0);
                }
            }
        }
    }
    __syncthreads();                     // done reading z buffers; reuse smem for transpose
    __bf16* tH = (__bf16*)smem;          // [144][136], byte stride 272 (16B-aligned)
    __bf16* tL = (__bf16*)(smem + 39168);
    #pragma unroll
    for (int kkt = 0; kkt < 9; ++kkt) {
        int kk = kkt * 16 + lm;
        float inv = nzinv[sb * KP + kk];
        float ss = 0.f;
        #pragma unroll
        for (int i = 0; i < 2; ++i) {
            bf16x4 h4, l4;
            #pragma unroll
            for (int e = 0; e < 4; ++e) {
                float val = acc[kkt][i][e] * inv;
                __bf16 h = (__bf16)val;
                __bf16 lo = (__bf16)(val - (float)h);
                float rec = (float)h + (float)lo;
                ss = fmaf(rec, rec, ss);
                int n = n0 + w * 32 + i * 16 + quad * 4 + e;
                if (wout && kk < K) out[(size_t)s * BNK + (size_t)(b * N + n) * K + kk] = val;
                h4[e] = h; l4[e] = lo;
            }
            int nloc = w * 32 + i * 16 + quad * 4;
            *(bf16x4*)(&tH[kk * 136 + nloc]) = h4;
            *(bf16x4*)(&tL[kk * 136 + nloc]) = l4;
        }
        ss += __shfl_xor(ss, 16, 64);    // reduce over quad (same lm == same kk)
        ss += __shfl_xor(ss, 32, 64);
        if (quad == 0) wsum[w * 144 + kk] = ss;
    }
    __syncthreads();
    if (t < KP) {
        float sum = wsum[t] + wsum[144 + t] + wsum[288 + t] + wsum[432 + t];
        nkp[((size_t)(sb * KP + t)) * 64 + ntile] = sum;
    }
    #pragma unroll
    for (int itc = 0; itc < 9; ++itc) {  // 144 rows x 16 x bf16x8 = 2304 slots / 256 thr
        int flat = itc * 256 + t;
        int row = flat >> 4, mm = flat & 15;
        size_t o = ((size_t)(sb * KP + row)) * N + n0 + mm * 8;
        *(bf16x8*)(kqh + o) = *(const bf16x8*)(&tH[row * 136 + mm * 8]);
        *(bf16x8*)(kql + o) = *(const bf16x8*)(&tL[row * 136 + mm * 8]);
    }
}

// ---------- final: out *= nkinv ----------
__global__ __launch_bounds__(256) void scale_kernel(float* __restrict__ out,
        const float* __restrict__ nkinv)
{
    int s = blockIdx.y;
    int idx = blockIdx.x * 256 + threadIdx.x;
    if (idx >= BNK) return;
    int kk = idx % K;
    int b = idx / (N * K);
    out[(size_t)s * BNK + idx] *= nkinv[SB(s,b) * KP + kk];
}

extern "C" void kernel_launch(void* const* d_in, const int* in_sizes, int n_in,
                              void* d_out, int out_size, void* d_ws, size_t ws_size,
                              hipStream_t stream)
{
    (void)in_sizes; (void)n_in; (void)out_size; (void)ws_size;
    const float* x1 = (const float*)d_in[0];
    const float* x2 = (const float*)d_in[1];
    float* out = (float*)d_out;
    char* w = (char*)d_ws;
    __bf16* kqh = (__bf16*)(w + OFS_KQH);
    __bf16* kql = (__bf16*)(w + OFS_KQL);
    float*  zp  = (float*)(w + OFS_ZP);
    float*  nzp = (float*)(w + OFS_ZT);   // reuse old zT slab for z sumsq partials
    __bf16* zh  = (__bf16*)(w + OFS_ZH);
    __bf16* zl  = (__bf16*)(w + OFS_ZL);
    float*  nki = (float*)(w + OFS_NKI);
    float*  nzi = (float*)(w + OFS_NZI);
    float*  nkp = (float*)(w + OFS_NKP);

    dim3 blk(256);
    pool_kernel <<<dim3(64*B, 2), blk, 0, stream>>>(x1, x2, kqh, kql, nkp);
    knorm_reduce<<<dim3((B*KP+255)/256, 2), blk, 0, stream>>>(nkp, nki, 64);

    for (int st = 0; st < 3; ++st) {
        gemm1_kernel  <<<dim3(256, 2), blk, 0, stream>>>(x1, x2, kqh, kql, nki, zp);
        softmax_kernel<<<dim3(B*C/16, 2), blk, 0, stream>>>(zp, zh, zl, nzp);
        znorm_kernel  <<<dim3((B*KP+255)/256, 2), blk, 0, stream>>>(nzp, nzi);
        gemm2_kernel  <<<dim3(32*B, 2), blk, 0, stream>>>(x1, x2, zh, zl, nzi, out, kqh, kql,
                                                          nkp, st == 2 ? 1 : 0);
        knorm_reduce  <<<dim3((B*KP+255)/256, 2), blk, 0, stream>>>(nkp, nki, 32);
    }
    scale_kernel    <<<dim3((BNK+255)/256, 2), blk, 0, stream>>>(out, nki);
}

// Round 9
// 473.055 us; speedup vs baseline: 1.0644x; 1.0644x over previous
//
#include <hip/hip_runtime.h>
#include <math.h>
#include <float.h>

#define B 8
#define N 4096
#define C 512
#define K 130
#define KP 144
#define BNK (B*N*K)
#define SB(s,b) ((s)*B + (b))

typedef __bf16 bf16x8 __attribute__((ext_vector_type(8)));
typedef __bf16 bf16x4 __attribute__((ext_vector_type(4)));
typedef float  f32x4  __attribute__((ext_vector_type(4)));

// ws layout (bytes); total ~86 MB (proven-safe: R1 ran at 160 MB)
#define SZ_KQ   18874368ull                 // bf16 [2][B][KP][N]
#define SLAB    1179648ull                  // floats per zpart slab: 16*KP*C
#define OFS_KQH 0ull
#define OFS_KQL (OFS_KQH + SZ_KQ)
#define OFS_ZP  (OFS_KQL + SZ_KQ)           // float [8][16][KP][C] partials
#define OFS_ZT  (OFS_ZP + 8ull*SLAB*4ull)   // reused: nzp partial sumsq [16][KP][32]
#define OFS_ZH  (OFS_ZT + SLAB*4ull)        // bf16
#define OFS_ZL  (OFS_ZH + SLAB*2ull)
#define OFS_NKI (OFS_ZL + SLAB*2ull)
#define OFS_NZI (OFS_NKI + 9216ull)
#define OFS_NKP (OFS_NZI + 9216ull)         // float [16][KP][64] kq sumsq partials

__device__ __forceinline__ void split2(float v, __bf16& h, __bf16& l) {
    h = (__bf16)v;
    l = (__bf16)(v - (float)h);
}
// split into ext-vector elements (can't bind refs to vector elements)
#define SPLIT_VEC(v, vh, vl, i) { __bf16 _h = (__bf16)(v); (vh)[i] = _h; (vl)[i] = (__bf16)((v) - (float)_h); }

// async global->LDS, 16B per lane; LDS dest = wave-uniform base + lane*16
__device__ __forceinline__ void gl_lds16(const void* g, void* l) {
    __builtin_amdgcn_global_load_lds(
        (const __attribute__((address_space(1))) void*)g,
        (__attribute__((address_space(3))) void*)l, 16, 0, 0);
}

// window max for one half: v = own chunk [4l,4l+4), u = next 4 elems [4l+4,4l+8)
// window = [4l+r, 4l+4+t): max(suffix of v from r, prefix of u of t elems)
__device__ __forceinline__ float wmax(float4 v, float4 u, int r, int tt, float& sm0out) {
    float sm3 = v.w;
    float sm2 = fmaxf(v.z, sm3);
    float sm1 = fmaxf(v.y, sm2);
    float sm0 = fmaxf(v.x, sm1);
    sm0out = sm0;
    float smr = (r == 3) ? sm3 : (r == 2) ? sm2 : (r == 1) ? sm1 : sm0;
    float pu1 = u.x;
    float pu2 = fmaxf(pu1, u.y);
    float pu3 = fmaxf(pu2, u.z);
    float pu4 = fmaxf(pu3, u.w);
    float put = (tt == 4) ? pu4 : (tt == 3) ? pu3 : (tt == 2) ? pu2 :
                (tt == 1) ? pu1 : -FLT_MAX;
    return fmaxf(smr, put);
}

// ---------- adaptive max pool from fp32 x -> kq hi/lo [s][b][kk][n] ----------
// v8: v7 ring pipeline (pool parked at ~60us: 6 structurally distinct variants
// identical -> throughput-resource-bound). Emits per-block kq sumsq partials.
__global__ __launch_bounds__(256) void pool_kernel(const float* __restrict__ x1,
        const float* __restrict__ x2, __bf16* __restrict__ kqh, __bf16* __restrict__ kql,
        float* __restrict__ nkp)
{
    int s = blockIdx.y;
    const float* x = s ? x2 : x1;
    int bx = blockIdx.x;                 // nch(64) * b(8)
    int nch = bx & 63, b = bx >> 6;
    int n0 = nch * 64;
    int t = threadIdx.x, w = t >> 6, l = t & 63;
    int sb = SB(s,b);

    __shared__ __align__(16) float spool[8192 + KP * 69 + 8];
    float* pooled = spool + 8192;

    int kkA = l + 1;
    int sA  = (kkA * 256) / 65;               // start (floor)
    int eA  = ((kkA + 1) * 256 + 64) / 65;    // end (ceil)
    int rwin = sA - 4 * l;                    // 0..3
    int tt   = eA - 4 * l - 4;                // 0..4

    size_t xbase = (size_t)(b * N + n0) * C;

#define ISSUE_ROW(rl, slot) { \
        const float* src_ = x + xbase + (size_t)(w * 16 + (rl)) * C + 4 * l; \
        char* dst_ = (char*)spool + (w * 4 + (slot)) * 2048; \
        gl_lds16(src_, dst_); \
        gl_lds16(src_ + 256, dst_ + 1024); \
    }

#define COMP_ROW(rl) { \
        const float* xr_ = spool + (w * 4 + ((rl) & 3)) * 512; \
        float4 vA = *(const float4*)(xr_ + 4 * l); \
        float4 uA = *(const float4*)(xr_ + 4 * l + 4); \
        float4 vB = *(const float4*)(xr_ + 256 + 4 * l); \
        float4 uB = *(const float4*)(xr_ + 256 + 4 * l + 4); \
        float sm0A, sm0B; \
        float mA = wmax(vA, uA, rwin, tt, sm0A); \
        float mB = wmax(vB, uB, rwin, tt, sm0B); \
        int n_ = w * 16 + (rl); \
        pooled[kkA * 69 + n_] = mA; \
        pooled[(kkA + 65) * 69 + n_] = mB; \
        if (l == 0) { pooled[n_] = sm0A; pooled[65 * 69 + n_] = sm0B; } \
    }

#define POOL_STEP(rl, VMC) \
    asm volatile("s_waitcnt vmcnt(" #VMC ")" ::: "memory"); \
    __builtin_amdgcn_sched_barrier(0); \
    COMP_ROW(rl) \
    __builtin_amdgcn_sched_barrier(0); \
    if ((rl) + 4 < 16) ISSUE_ROW((rl) + 4, (rl) & 3)

    ISSUE_ROW(0, 0) ISSUE_ROW(1, 1) ISSUE_ROW(2, 2) ISSUE_ROW(3, 3)

    POOL_STEP(0, 6);  POOL_STEP(1, 6);  POOL_STEP(2, 6);  POOL_STEP(3, 6);
    POOL_STEP(4, 6);  POOL_STEP(5, 6);  POOL_STEP(6, 6);  POOL_STEP(7, 6);
    POOL_STEP(8, 6);  POOL_STEP(9, 6);  POOL_STEP(10, 6); POOL_STEP(11, 6);
    POOL_STEP(12, 6); POOL_STEP(13, 4); POOL_STEP(14, 2); POOL_STEP(15, 0);

#undef POOL_STEP
#undef COMP_ROW
#undef ISSUE_ROW

    __syncthreads();
    int g = t >> 3, j = t & 7;
    #pragma unroll
    for (int p = 0; p < 9; ++p) {
        int task = p * 32 + g;           // < 288
        int a = task >= 144;
        int kk = task - (a ? 144 : 0);
        bf16x8 v8;
        float ss = 0.f;
        #pragma unroll
        for (int e = 0; e < 8; ++e) {
            float val = (kk < K) ? pooled[kk * 69 + j * 8 + e] : 0.f;
            __bf16 h = (__bf16)val;
            __bf16 lo = (__bf16)(val - (float)h);
            v8[e] = a ? lo : h;
            float rec = (float)h + (float)lo;
            ss = fmaf(rec, rec, ss);
        }
        __bf16* dst = a ? kql : kqh;
        *(bf16x8*)(dst + ((size_t)(sb * KP + kk)) * N + n0 + j * 8) = v8;
        if (!a) {
            ss += __shfl_xor(ss, 1, 8);
            ss += __shfl_xor(ss, 2, 8);
            ss += __shfl_xor(ss, 4, 8);
            if (j == 0) nkp[((size_t)(sb * KP + kk)) * 64 + nch] = ss;
        }
    }
}

// ---------- norm reduce (coalesced): one wave per row, lane l loads p[row*stride+l],
// shuffle-tree sum -> 1/(1e-6+sqrt). Replaces knorm_reduce AND znorm. ----------
__global__ __launch_bounds__(256) void norm_reduce(const float* __restrict__ p,
        float* __restrict__ o, int stride, int cnt)
{
    int s = blockIdx.y;
    int w = threadIdx.x >> 6, l = threadIdx.x & 63;
    int row = blockIdx.x * 4 + w;        // < B*KP
    const float* pp = p + ((size_t)(s * B * KP) + row) * stride;
    float v = (l < cnt) ? pp[l] : 0.f;
    #pragma unroll
    for (int off = 32; off; off >>= 1) v += __shfl_xor(v, off, 64);
    if (l == 0) o[s * B * KP + row] = 1.f / (1e-6f + sqrtf(v));
}

// ---------- GEMM1 (split): zpart[p][kk][c] = sum_n kq[kk][n]*x[n][c] * nkinv[kk] ----------
__device__ __forceinline__ void stage_kq(const __bf16* kqh, const __bf16* kql,
        size_t kqbase, int nb, int gsl, char* buf, int w, int l)
{
    #pragma unroll
    for (int i = 0; i < 5; ++i) {
        int j = i * 4 + w;               // 18 wave-issues
        if (j < 18) {
            int rbase = j * 16;          // LDS rows (hi: 0..143, lo: 144..287)
            int kk = rbase + (l >> 2) - (j >= 9 ? 144 : 0);
            const __bf16* bp = (j >= 9) ? kql : kqh;
            gl_lds16(bp + kqbase + (size_t)kk * N + nb + gsl, buf + rbase * 64);
        }
    }
}

__global__ __launch_bounds__(256, 2) void gemm1_kernel(const float* __restrict__ x1,
        const float* __restrict__ x2, const __bf16* __restrict__ kqh,
        const __bf16* __restrict__ kql, const float* __restrict__ nkinv,
        float* __restrict__ zpart)
{
    int s = blockIdx.y;
    const float* x = s ? x2 : x1;
    int orig = blockIdx.x;               // 256 blocks: XCD swizzle (bijective)
    int wid = (orig & 7) * 32 + (orig >> 3);
    int cs = wid & 3, b = (wid >> 2) & 7, nsp = wid >> 5;
    int sb = SB(s,b);
    int c0 = cs * 128, n0 = nsp * 512;
    int t = threadIdx.x, w = t >> 6, l = t & 63, quad = l >> 4, lm = l & 15;

    __shared__ __bf16 ldsh[128 * 40];
    __shared__ __bf16 ldsl[128 * 40];
    __shared__ __align__(16) char kbuf[2][18432];  // [288 rows][64B], slot^((row>>1)&3)

    f32x4 acc[9][2];
    #pragma unroll
    for (int kkt = 0; kkt < 9; ++kkt)
        #pragma unroll
        for (int ct = 0; ct < 2; ++ct) { acc[kkt][ct][0]=0.f; acc[kkt][ct][1]=0.f; acc[kkt][ct][2]=0.f; acc[kkt][ct][3]=0.f; }

    int cload = t & 127;
    int ngrp = t >> 7;
    size_t kqbase = (size_t)(sb * KP) * N;
    int gsl = ((l & 3) ^ ((l >> 3) & 3)) * 8;      // inverse-swizzled src n-offset

    float xr[16];
    {
        const float* xs = x + (size_t)(b * N + n0 + ngrp * 16) * C + c0 + cload;
        #pragma unroll
        for (int p = 0; p < 16; ++p) xr[p] = xs[(size_t)p * C];
        stage_kq(kqh, kql, kqbase, n0, gsl, kbuf[0], w, l);
    }

    for (int step = 0; step < 16; ++step) {
        int nb = n0 + step * 32;
        __syncthreads();
        #pragma unroll
        for (int p = 0; p < 4; ++p) {    // split regs -> lds [c][n] hi/lo
            int nl = ngrp * 16 + p * 4;
            bf16x4 vh, vl;
            SPLIT_VEC(xr[p*4+0], vh, vl, 0); SPLIT_VEC(xr[p*4+1], vh, vl, 1);
            SPLIT_VEC(xr[p*4+2], vh, vl, 2); SPLIT_VEC(xr[p*4+3], vh, vl, 3);
            *(bf16x4*)(&ldsh[cload * 40 + nl]) = vh;
            *(bf16x4*)(&ldsl[cload * 40 + nl]) = vl;
        }
        __syncthreads();
        if (step < 15) {
            int nb2 = nb + 32;
            stage_kq(kqh, kql, kqbase, nb2, gsl, kbuf[(step + 1) & 1], w, l);
            const float* xs = x + (size_t)(b * N + nb2 + ngrp * 16) * C + c0 + cload;
            #pragma unroll
            for (int p = 0; p < 16; ++p) xr[p] = xs[(size_t)p * C];
        }
        const char* kb = kbuf[step & 1];
        bf16x8 bh[2], bl[2];
        #pragma unroll
        for (int ct = 0; ct < 2; ++ct) {
            int cl = w * 32 + ct * 16 + lm;
            bh[ct] = *(const bf16x8*)(&ldsh[cl * 40 + quad * 8]);
            bl[ct] = *(const bf16x8*)(&ldsl[cl * 40 + quad * 8]);
        }
        int arow = lm * 64 + ((quad ^ ((lm >> 1) & 3)) * 16);
        #pragma unroll
        for (int kkt = 0; kkt < 9; ++kkt) {
            bf16x8 ah = *(const bf16x8*)(kb + kkt * 1024 + arow);
            bf16x8 al = *(const bf16x8*)(kb + 9216 + kkt * 1024 + arow);
            #pragma unroll
            for (int ct = 0; ct < 2; ++ct) {
                acc[kkt][ct] = __builtin_amdgcn_mfma_f32_16x16x32_bf16(ah, bh[ct], acc[kkt][ct], 0, 0, 0);
                acc[kkt][ct] = __builtin_amdgcn_mfma_f32_16x16x32_bf16(al, bh[ct], acc[kkt][ct], 0, 0, 0);
                acc[kkt][ct] = __builtin_amdgcn_mfma_f32_16x16x32_bf16(ah, bl[ct], acc[kkt][ct], 0, 0, 0);
            }
        }
    }
    float* zp = zpart + ((size_t)nsp * 16 + sb) * KP * C;
    #pragma unroll
    for (int kkt = 0; kkt < 9; ++kkt) {
        #pragma unroll
        for (int i = 0; i < 4; ++i) {
            int kk = kkt * 16 + quad * 4 + i;
            float inv = nkinv[sb * KP + kk];
            #pragma unroll
            for (int ct = 0; ct < 2; ++ct) {
                int c = c0 + w * 32 + ct * 16 + lm;
                zp[(size_t)kk * C + c] = acc[kkt][ct][i] * inv;
            }
        }
    }
}

// ---------- softmax (fused): sum 8 partials in LDS, softmax over kk,
// write zh/zl ONLY, emit per-block sumsq partials for znorm. ----------
__global__ __launch_bounds__(256) void softmax_kernel(const float* __restrict__ zpart,
        __bf16* __restrict__ zh, __bf16* __restrict__ zl, float* __restrict__ nzp)
{
    int s = blockIdx.y;
    int bx = blockIdx.x;                 // b(8) * cb(32)
    int b = bx >> 5, cb = bx & 31;
    int c0 = cb * 16;
    int sb = SB(s,b);
    int t = threadIdx.x;
    int cl = t & 15, g = t >> 4;         // 16 kk-groups
    __shared__ float sm[KP * 17];
    __shared__ float inv[16];
    size_t base = (size_t)sb * KP * C + c0 + cl;

    #pragma unroll
    for (int j = 0; j < 9; ++j) {
        int kk = g + 16 * j;             // covers 0..143
        size_t off = base + (size_t)kk * C;
        float v = 0.f;
        #pragma unroll
        for (int p = 0; p < 8; ++p)
            v += zpart[(size_t)p * SLAB + off];
        sm[kk * 17 + cl] = v;
    }
    __syncthreads();
    {
        int c = t >> 4, r = t & 15;
        float m = -FLT_MAX;
        for (int kk = r; kk < K; kk += 16) m = fmaxf(m, sm[kk * 17 + c]);
        m = fmaxf(m, __shfl_xor(m, 1, 64));
        m = fmaxf(m, __shfl_xor(m, 2, 64));
        m = fmaxf(m, __shfl_xor(m, 4, 64));
        m = fmaxf(m, __shfl_xor(m, 8, 64));
        float sum = 0.f;
        for (int kk = r; kk < K; kk += 16) {
            float e = expf(sm[kk * 17 + c] - m);
            sm[kk * 17 + c] = e;
            sum += e;
        }
        sum += __shfl_xor(sum, 1, 64);
        sum += __shfl_xor(sum, 2, 64);
        sum += __shfl_xor(sum, 4, 64);
        sum += __shfl_xor(sum, 8, 64);
        if (r == 0) inv[c] = 1.f / sum;
    }
    __syncthreads();
    #pragma unroll
    for (int j = 0; j < 9; ++j) {
        int kk = g + 16 * j;
        float val = (kk < K) ? sm[kk * 17 + cl] * inv[cl] : 0.f;
        __bf16 h, lo; split2(val, h, lo);
        size_t off = base + (size_t)kk * C;
        zh[off] = h;
        zl[off] = lo;
        float ss = val * val;
        #pragma unroll
        for (int o = 8; o; o >>= 1) ss += __shfl_xor(ss, o, 16);
        if (cl == 0) nzp[((size_t)sb * KP + kk) * 32 + cb] = ss;
    }
}

// ---------- GEMM2 (split): kq_new[kk][n] = sum_c x[n][c]*z[kk][c] * nzinv[kk] ----------
// v4: out-write removed entirely (emit_out reconstructs out from kq hi/lo).
//     z hi/lo LDS-staged, 128 n/block, XCD swizzle, nkp sumsq partials.
__global__ __launch_bounds__(256, 2) void gemm2_kernel(const float* __restrict__ x1,
        const float* __restrict__ x2, const __bf16* __restrict__ zh,
        const __bf16* __restrict__ zl, const float* __restrict__ nzinv,
        __bf16* __restrict__ kqh, __bf16* __restrict__ kql,
        float* __restrict__ nkp)
{
    int s = blockIdx.y;
    const float* x = s ? x2 : x1;
    int orig = blockIdx.x;
    int bx = (orig & 7) * 32 + (orig >> 3);
    int ntile = bx & 31, b = bx >> 5, sb = SB(s,b);
    int n0 = ntile * 128;
    int t = threadIdx.x, w = t >> 6, l = t & 63, quad = l >> 4, lm = l & 15;

    __shared__ __align__(16) char smem[80640];
    float* wsum = (float*)(smem + 78336);    // [4][144]

    f32x4 acc[9][2];
    #pragma unroll
    for (int kkt = 0; kkt < 9; ++kkt)
        #pragma unroll
        for (int i = 0; i < 2; ++i) { acc[kkt][i][0]=0.f; acc[kkt][i][1]=0.f; acc[kkt][i][2]=0.f; acc[kkt][i][3]=0.f; }

    size_t zrb = (size_t)sb * KP * C;
    int lr = l >> 3, m8 = l & 7;
    int csw = ((m8 ^ lr) * 8);

    #pragma unroll
    for (int i = 0; i < 9; ++i) {
        int r0 = (w * 9 + i) * 8, row = r0 + lr;
        const __bf16* src = (row < KP) ? (zh + zrb + (size_t)row * C + csw)
                                       : (zl + zrb + (size_t)(row - KP) * C + csw);
        gl_lds16(src, smem + r0 * 128);
    }

    for (int it = 0; it < 8; ++it) {
        __syncthreads();
        if (it < 7) {
            int cb2 = (it + 1) * 64;
            char* buf = smem + ((it + 1) & 1) * 36864;
            #pragma unroll
            for (int i = 0; i < 9; ++i) {
                int r0 = (w * 9 + i) * 8, row = r0 + lr;
                const __bf16* src = (row < KP) ? (zh + zrb + (size_t)row * C + cb2 + csw)
                                               : (zl + zrb + (size_t)(row - KP) * C + cb2 + csw);
                gl_lds16(src, buf + r0 * 128);
            }
        }
        const char* zb = smem + (it & 1) * 36864;
        int cb = it * 64;
        #pragma unroll
        for (int sub = 0; sub < 2; ++sub) {
            bf16x8 ah[2], al[2];
            #pragma unroll
            for (int i = 0; i < 2; ++i) {
                const float* Ab = x + (size_t)(b * N + n0 + w * 32 + i * 16 + lm) * C + cb + sub * 32 + quad * 8;
                float4 u = *(const float4*)Ab;
                float4 v = *(const float4*)(Ab + 4);
                SPLIT_VEC(u.x, ah[i], al[i], 0); SPLIT_VEC(u.y, ah[i], al[i], 1);
                SPLIT_VEC(u.z, ah[i], al[i], 2); SPLIT_VEC(u.w, ah[i], al[i], 3);
                SPLIT_VEC(v.x, ah[i], al[i], 4); SPLIT_VEC(v.y, ah[i], al[i], 5);
                SPLIT_VEC(v.z, ah[i], al[i], 6); SPLIT_VEC(v.w, ah[i], al[i], 7);
            }
            int sw = ((sub * 4 + quad) ^ (lm & 7)) * 16;
            #pragma unroll
            for (int kkt = 0; kkt < 9; ++kkt) {
                int kk = kkt * 16 + lm;
                const char* ph = zb + kk * 128 + sw;
                bf16x8 bh = *(const bf16x8*)ph;
                bf16x8 bl = *(const bf16x8*)(ph + KP * 128);
                #pragma unroll
                for (int i = 0; i < 2; ++i) {
                    acc[kkt][i] = __builtin_amdgcn_mfma_f32_16x16x32_bf16(ah[i], bh, acc[kkt][i], 0, 0, 0);
                    acc[kkt][i] = __builtin_amdgcn_mfma_f32_16x16x32_bf16(al[i], bh, acc[kkt][i], 0, 0, 0);
                    acc[kkt][i] = __builtin_amdgcn_mfma_f32_16x16x32_bf16(ah[i], bl, acc[kkt][i], 0, 0, 0);
                }
            }
        }
    }
    __syncthreads();
    __bf16* tH = (__bf16*)smem;          // [144][136]
    __bf16* tL = (__bf16*)(smem + 39168);
    #pragma unroll
    for (int kkt = 0; kkt < 9; ++kkt) {
        int kk = kkt * 16 + lm;
        float inv = nzinv[sb * KP + kk];
        float ss = 0.f;
        #pragma unroll
        for (int i = 0; i < 2; ++i) {
            bf16x4 h4, l4;
            #pragma unroll
            for (int e = 0; e < 4; ++e) {
                float val = acc[kkt][i][e] * inv;
                __bf16 h = (__bf16)val;
                __bf16 lo = (__bf16)(val - (float)h);
                float rec = (float)h + (float)lo;
                ss = fmaf(rec, rec, ss);
                h4[e] = h; l4[e] = lo;
            }
            int nloc = w * 32 + i * 16 + quad * 4;
            *(bf16x4*)(&tH[kk * 136 + nloc]) = h4;
            *(bf16x4*)(&tL[kk * 136 + nloc]) = l4;
        }
        ss += __shfl_xor(ss, 16, 64);
        ss += __shfl_xor(ss, 32, 64);
        if (quad == 0) wsum[w * 144 + kk] = ss;
    }
    __syncthreads();
    if (t < KP) {
        float sum = wsum[t] + wsum[144 + t] + wsum[288 + t] + wsum[432 + t];
        nkp[((size_t)(sb * KP + t)) * 64 + ntile] = sum;
    }
    #pragma unroll
    for (int itc = 0; itc < 9; ++itc) {
        int flat = itc * 256 + t;
        int row = flat >> 4, mm = flat & 15;
        size_t o = ((size_t)(sb * KP + row)) * N + n0 + mm * 8;
        *(bf16x8*)(kqh + o) = *(const bf16x8*)(&tH[row * 136 + mm * 8]);
        *(bf16x8*)(kql + o) = *(const bf16x8*)(&tL[row * 136 + mm * 8]);
    }
}

// ---------- emit out: out[n][kk] = (kqh+kql)[kk][n] * nkinv[kk], transposed ----------
// Read coalesced bf16x8 along n; write is a CONTIGUOUS f32 stream:
// out slice for (b, n0..n0+64) is 64*130 consecutive floats (i = n*130+kk).
__global__ __launch_bounds__(256) void emit_out(const __bf16* __restrict__ kqh,
        const __bf16* __restrict__ kql, const float* __restrict__ nkinv,
        float* __restrict__ out)
{
    int s = blockIdx.y;
    int bx = blockIdx.x;                 // nch(64) * b(8)
    int nch = bx & 63, b = bx >> 6;
    int n0 = nch * 64;
    int sb = SB(s,b);
    int t = threadIdx.x;

    __shared__ float tile[K * 65];       // [kk][n], odd stride
    __shared__ float nkl[K];

    if (t < K) nkl[t] = nkinv[sb * KP + t];
    // load K rows x 64 n: 130*8 = 1040 (row, 8n-group) tasks
    #pragma unroll
    for (int it = 0; it < 5; ++it) {
        int flat = it * 256 + t;
        if (flat < K * 8) {
            int row = flat >> 3, grp = flat & 7;
            size_t o = ((size_t)(sb * KP + row)) * N + n0 + grp * 8;
            bf16x8 h8 = *(const bf16x8*)(kqh + o);
            bf16x8 l8 = *(const bf16x8*)(kql + o);
            #pragma unroll
            for (int e = 0; e < 8; ++e)
                tile[row * 65 + grp * 8 + e] = (float)h8[e] + (float)l8[e];
        }
    }
    __syncthreads();
    float* base = out + (size_t)s * BNK + (size_t)(b * N + n0) * K;
    for (int i = t; i < 64 * K; i += 256) {
        int n = i / K, kk = i - n * K;
        base[i] = tile[kk * 65 + n] * nkl[kk];
    }
}

extern "C" void kernel_launch(void* const* d_in, const int* in_sizes, int n_in,
                              void* d_out, int out_size, void* d_ws, size_t ws_size,
                              hipStream_t stream)
{
    (void)in_sizes; (void)n_in; (void)out_size; (void)ws_size;
    const float* x1 = (const float*)d_in[0];
    const float* x2 = (const float*)d_in[1];
    float* out = (float*)d_out;
    char* w = (char*)d_ws;
    __bf16* kqh = (__bf16*)(w + OFS_KQH);
    __bf16* kql = (__bf16*)(w + OFS_KQL);
    float*  zp  = (float*)(w + OFS_ZP);
    float*  nzp = (float*)(w + OFS_ZT);   // z sumsq partials
    __bf16* zh  = (__bf16*)(w + OFS_ZH);
    __bf16* zl  = (__bf16*)(w + OFS_ZL);
    float*  nki = (float*)(w + OFS_NKI);
    float*  nzi = (float*)(w + OFS_NZI);
    float*  nkp = (float*)(w + OFS_NKP);

    dim3 blk(256);
    pool_kernel <<<dim3(64*B, 2), blk, 0, stream>>>(x1, x2, kqh, kql, nkp);
    norm_reduce <<<dim3(B*KP/4, 2), blk, 0, stream>>>(nkp, nki, 64, 64);

    for (int st = 0; st < 3; ++st) {
        gemm1_kernel  <<<dim3(256, 2), blk, 0, stream>>>(x1, x2, kqh, kql, nki, zp);
        softmax_kernel<<<dim3(B*C/16, 2), blk, 0, stream>>>(zp, zh, zl, nzp);
        norm_reduce   <<<dim3(B*KP/4, 2), blk, 0, stream>>>(nzp, nzi, 32, 32);
        gemm2_kernel  <<<dim3(32*B, 2), blk, 0, stream>>>(x1, x2, zh, zl, nzi, kqh, kql, nkp);
        norm_reduce   <<<dim3(B*KP/4, 2), blk, 0, stream>>>(nkp, nki, 64, 32);
    }
    emit_out        <<<dim3(64*B, 2), blk, 0, stream>>>(kqh, kql, nki, out);
}